// Round 6
// baseline (241.442 us; speedup 1.0000x reference)
//
#include <hip/hip_runtime.h>

#define ROWS 4096
#define NCOL 8192
#define THREADS 256
#define WAVES (THREADS / 64)          // 4
#define CPT 8                         // float4 chunks per thread per row (8*4*256 = 8192)
#define RPB 8                         // rows per block
#define GRID (ROWS / RPB)             // 512 = 2 blocks/CU
#define CAP 256

// Async global->LDS, 16B per lane. LDS dest must be wave-uniform base (HW adds lane*16).
__device__ __forceinline__ void gload_lds16(const float4* g, float4* l) {
    __builtin_amdgcn_global_load_lds(
        (const __attribute__((address_space(1))) void*)g,
        (__attribute__((address_space(3))) void*)l,
        16, 0, 0);
}

__global__ __launch_bounds__(THREADS, 2)
void sparsemax_kernel(const float* __restrict__ x, float* __restrict__ out) {
    const int tid  = threadIdx.x;
    const int wave = tid >> 6;
    const int lane = tid & 63;
    const int row0 = blockIdx.x * RPB;

    __shared__ float4 buf[2][NCOL / 4];   // 2 x 32 KiB double buffer (wave-private chunks)
    __shared__ float  cand[2][CAP];
    __shared__ int    scnt[2];
    __shared__ float  swm[WAVES], swe[WAVES], swv[WAVES];
    __shared__ int    swk[WAVES];

    if (tid < 2) scnt[tid] = 0;
    __syncthreads();                      // before any loads: drains nothing

    // Prologue: issue row 0 into buf[0] (8 async loads per wave).
    {
        const float4* xr = (const float4*)(x + (size_t)row0 * NCOL);
#pragma unroll
        for (int j = 0; j < CPT; ++j) {
            const int c = wave * CPT + j;                 // chunk 0..31, wave-owned
            gload_lds16(xr + (c * 64 + lane), &buf[0][c * 64]);
        }
    }

    for (int r = 0; r < RPB; ++r) {
        const int cur = r & 1;
        const int nxt = cur ^ 1;

        // [A] issue NEXT row's loads now; they stay in flight across the raw barriers
        //     below (no vmcnt drain anywhere in the fast path).
        if (r + 1 < RPB) {
            const float4* xr = (const float4*)(x + (size_t)(row0 + r + 1) * NCOL);
#pragma unroll
            for (int j = 0; j < CPT; ++j) {
                const int c = wave * CPT + j;
                gload_lds16(xr + (c * 64 + lane), &buf[nxt][c * 64]);
            }
        }

        // [B] counted wait: retire only THIS row's 8 loads.
        // vmcnt queue (issue order): [row r loads(8)] [row r-1 stores(8) if r>=1]
        //                            [row r+1 loads(8) if r<RPB-1]
        if (r == 0 || r == RPB - 1) {
            asm volatile("s_waitcnt vmcnt(8)" ::: "memory");
        } else {
            asm volatile("s_waitcnt vmcnt(16)" ::: "memory");
        }

        // [C] the single scan: online top-4 + evicted-max over own wave-private slots.
        float c0 = -INFINITY, c1 = -INFINITY, c2 = -INFINITY, c3 = -INFINITY;
        float ev = -INFINITY;
#define INS(qv) do {                                    \
        float n = (qv), mx;                             \
        mx = fmaxf(c0, n); n = fminf(c0, n); c0 = mx;   \
        mx = fmaxf(c1, n); n = fminf(c1, n); c1 = mx;   \
        mx = fmaxf(c2, n); n = fminf(c2, n); c2 = mx;   \
        mx = fmaxf(c3, n); n = fminf(c3, n); c3 = mx;   \
        ev = fmaxf(ev, n);                              \
    } while (0)
#pragma unroll
        for (int j = 0; j < CPT; ++j) {
            float4 q = buf[cur][(wave * CPT + j) * 64 + lane];
            INS(q.x); INS(q.y); INS(q.z); INS(q.w);
        }
#undef INS

        // [D] wave reduce (max, evicted-max)
        float m = c0, ew = ev;
#pragma unroll
        for (int off = 32; off > 0; off >>= 1) {
            m  = fmaxf(m,  __shfl_xor(m,  off, 64));
            ew = fmaxf(ew, __shfl_xor(ew, off, 64));
        }
        if (lane == 0) { swm[wave] = m; swe[wave] = ew; }

        // [E] raw barrier: order LDS only (lgkmcnt). Global loads keep flying.
        asm volatile("s_waitcnt lgkmcnt(0)\n\ts_barrier" ::: "memory");

        float bm = swm[0], be = swe[0];
#pragma unroll
        for (int w = 1; w < WAVES; ++w) { bm = fmaxf(bm, swm[w]); be = fmaxf(be, swe[w]); }
        const float t0 = bm - 1.0f;       // tau* >= max-1

        if (tid == 0) scnt[nxt] = 0;      // last reader passed [E]; sealed by [G]

        // [F] push candidates (> t0) from per-thread top-4 (expected ~21 total)
        if (c0 > t0) { int p = atomicAdd(&scnt[cur], 1); if (p < CAP) cand[cur][p] = c0; }
        if (c1 > t0) { int p = atomicAdd(&scnt[cur], 1); if (p < CAP) cand[cur][p] = c1; }
        if (c2 > t0) { int p = atomicAdd(&scnt[cur], 1); if (p < CAP) cand[cur][p] = c2; }
        if (c3 > t0) { int p = atomicAdd(&scnt[cur], 1); if (p < CAP) cand[cur][p] = c3; }

        // [G] raw barrier (LDS only).
        asm volatile("s_waitcnt lgkmcnt(0)\n\ts_barrier" ::: "memory");

        const int k0 = scnt[cur];
        float t = t0;
        bool need_full = (k0 > CAP);

        if (!need_full) {
            // Wave-redundant Michelot on the tiny list: shuffle-only, no barriers,
            // bitwise-identical result in every wave.
            const float q0 = (lane       < k0) ? cand[cur][lane      ] : -INFINITY;
            const float q1 = (lane + 64  < k0) ? cand[cur][lane + 64 ] : -INFINITY;
            const float q2 = (lane + 128 < k0) ? cand[cur][lane + 128] : -INFINITY;
            const float q3 = (lane + 192 < k0) ? cand[cur][lane + 192] : -INFINITY;
            int prev_k = -1;
            for (int it = 0; it < 64; ++it) {
                float s = 0.0f; int k = 0;
                if (q0 > t) { s += q0; ++k; }
                if (q1 > t) { s += q1; ++k; }
                if (q2 > t) { s += q2; ++k; }
                if (q3 > t) { s += q3; ++k; }
#pragma unroll
                for (int off = 32; off > 0; off >>= 1) {
                    s += __shfl_xor(s, off, 64);
                    k += __shfl_xor(k, off, 64);
                }
                if (k == prev_k) break;   // support stable => fixed point reached
                prev_k = k;
                t = (s - 1.0f) / (float)k;
            }
            // Validity: any evicted value above tau means the candidate union may
            // have missed support elements -> exact fallback.
            need_full = (be > t);
        }

        if (need_full) {
            // Exact fallback (cold; block-uniform decision). Full drains here are OK.
            int prev_k = -1;
            for (int it = 0; it < 200; ++it) {
                float s = 0.0f; int k = 0;
#pragma unroll
                for (int j = 0; j < CPT; ++j) {
                    float4 q = buf[cur][(wave * CPT + j) * 64 + lane];
                    if (q.x > t) { s += q.x; ++k; }
                    if (q.y > t) { s += q.y; ++k; }
                    if (q.z > t) { s += q.z; ++k; }
                    if (q.w > t) { s += q.w; ++k; }
                }
#pragma unroll
                for (int off = 32; off > 0; off >>= 1) {
                    s += __shfl_xor(s, off, 64);
                    k += __shfl_xor(k, off, 64);
                }
                if (lane == 0) { swv[wave] = s; swk[wave] = k; }
                __syncthreads();
                float st = 0.0f; int kt = 0;
#pragma unroll
                for (int w = 0; w < WAVES; ++w) { st += swv[w]; kt += swk[w]; }
                __syncthreads();
                if (kt == prev_k) break;
                prev_k = kt;
                t = (st - 1.0f) / (float)kt;
            }
        }

        // [I] epilogue: re-read own slots from LDS, coalesced stores. The ds_reads
        // retire (same-wave order) before next iteration's [A] can touch this buffer,
        // and buf chunks are wave-private -> no barrier needed.
        {
            float4* outr = (float4*)(out + (size_t)(row0 + r) * NCOL);
#pragma unroll
            for (int j = 0; j < CPT; ++j) {
                const int idx = (wave * CPT + j) * 64 + lane;
                float4 q = buf[cur][idx];
                float4 o;
                o.x = fmaxf(q.x - t, 0.0f);
                o.y = fmaxf(q.y - t, 0.0f);
                o.z = fmaxf(q.z - t, 0.0f);
                o.w = fmaxf(q.w - t, 0.0f);
                outr[idx] = o;
            }
        }
    }
}

extern "C" void kernel_launch(void* const* d_in, const int* in_sizes, int n_in,
                              void* d_out, int out_size, void* d_ws, size_t ws_size,
                              hipStream_t stream) {
    const float* x = (const float*)d_in[0];
    float* out = (float*)d_out;
    sparsemax_kernel<<<GRID, THREADS, 0, stream>>>(x, out);
}